// Round 1
// baseline (234.332 us; speedup 1.0000x reference)
//
#include <hip/hip_runtime.h>

#define B 256
#define N_IN 1152
#define D_IN 8
#define N_OUT 10
#define D_OUT 16
#define NC 32                      // n's per block
#define NG (N_IN / NC)             // 36 n-groups
#define BPB 16                     // batches per block
#define NBG (B / BPB)              // 16 b-groups
#define OJ (N_OUT * D_OUT)         // 160
#define PSTRIDE (B * OJ)           // 40960 floats per n-group partial

// ---------------- pass 1: uniform coupling (c = 1/10, folded into reduce) ----------------
__global__ __launch_bounds__(256) void caps_pass1(const float* __restrict__ x,
                                                  const float* __restrict__ W,
                                                  float* __restrict__ P) {
  const int ng = blockIdx.x;
  const int bg = blockIdx.y;
  const int tid = threadIdx.x;
  const int bb = tid >> 4;        // batch within block
  const int j  = tid & 15;        // output-capsule dim lane
  const int b  = bg * BPB + bb;
  const int n0 = ng * NC;

  float s[N_OUT];
#pragma unroll
  for (int o = 0; o < N_OUT; ++o) s[o] = 0.f;

  const float* xp = &x[(size_t)(b * N_IN + n0) * D_IN];
  const float* Wp = &W[((size_t)n0 * N_OUT * D_OUT + j) * D_IN];

  for (int nn = 0; nn < NC; ++nn) {
    const float4 xa = *reinterpret_cast<const float4*>(xp);
    const float4 xb = *reinterpret_cast<const float4*>(xp + 4);
#pragma unroll
    for (int o = 0; o < N_OUT; ++o) {
      const float4 wa = *reinterpret_cast<const float4*>(Wp + o * (D_OUT * D_IN));
      const float4 wb = *reinterpret_cast<const float4*>(Wp + o * (D_OUT * D_IN) + 4);
      float u = wa.x*xa.x + wa.y*xa.y + wa.z*xa.z + wa.w*xa.w
              + wb.x*xb.x + wb.y*xb.y + wb.z*xb.z + wb.w*xb.w;
      s[o] += u;
    }
    xp += D_IN;
    Wp += N_OUT * D_OUT * D_IN;
  }

  float* Pp = &P[(size_t)(ng * B + b) * OJ + j];
#pragma unroll
  for (int o = 0; o < N_OUT; ++o) Pp[o * D_OUT] = s[o];
}

// ---------------- pass 2/3: logits = u_hat . veff, softmax over o, weighted sum ----------------
__global__ __launch_bounds__(256) void caps_pass23(const float* __restrict__ x,
                                                   const float* __restrict__ W,
                                                   const float* __restrict__ veff,
                                                   float* __restrict__ P) {
  __shared__ float v_lds[BPB][OJ];
  const int ng = blockIdx.x;
  const int bg = blockIdx.y;
  const int tid = threadIdx.x;
  const int bb = tid >> 4;
  const int j  = tid & 15;
  const int b  = bg * BPB + bb;
  const int n0 = ng * NC;

  // stage effective v for this block's 16 batches (16*160 = 2560 floats)
  for (int t = tid; t < BPB * OJ; t += 256) {
    const int lb = t / OJ, idx = t % OJ;
    v_lds[lb][idx] = veff[(size_t)(bg * BPB + lb) * OJ + idx];
  }
  __syncthreads();

  // hoist this thread's v values (n-invariant)
  float vj[N_OUT];
#pragma unroll
  for (int o = 0; o < N_OUT; ++o) vj[o] = v_lds[bb][o * D_OUT + j];

  float s[N_OUT];
#pragma unroll
  for (int o = 0; o < N_OUT; ++o) s[o] = 0.f;

  const float* xp = &x[(size_t)(b * N_IN + n0) * D_IN];
  const float* Wp = &W[((size_t)n0 * N_OUT * D_OUT + j) * D_IN];

  for (int nn = 0; nn < NC; ++nn) {
    const float4 xa = *reinterpret_cast<const float4*>(xp);
    const float4 xb = *reinterpret_cast<const float4*>(xp + 4);
    float u[N_OUT];
#pragma unroll
    for (int o = 0; o < N_OUT; ++o) {
      const float4 wa = *reinterpret_cast<const float4*>(Wp + o * (D_OUT * D_IN));
      const float4 wb = *reinterpret_cast<const float4*>(Wp + o * (D_OUT * D_IN) + 4);
      u[o] = wa.x*xa.x + wa.y*xa.y + wa.z*xa.z + wa.w*xa.w
           + wb.x*xb.x + wb.y*xb.y + wb.z*xb.z + wb.w*xb.w;
    }
    // logits b[o] = sum_j u[o,j] * veff[o,j]  (16-lane butterfly)
    float lg[N_OUT];
#pragma unroll
    for (int o = 0; o < N_OUT; ++o) {
      float r = u[o] * vj[o];
      r += __shfl_xor(r, 1, 16);
      r += __shfl_xor(r, 2, 16);
      r += __shfl_xor(r, 4, 16);
      r += __shfl_xor(r, 8, 16);
      lg[o] = r;
    }
    // softmax over o (thread-local; all 16 lanes hold identical lg[])
    float m = lg[0];
#pragma unroll
    for (int o = 1; o < N_OUT; ++o) m = fmaxf(m, lg[o]);
    float e[N_OUT], Z = 0.f;
#pragma unroll
    for (int o = 0; o < N_OUT; ++o) { e[o] = __expf(lg[o] - m); Z += e[o]; }
    const float invZ = 1.f / Z;
#pragma unroll
    for (int o = 0; o < N_OUT; ++o) s[o] += (e[o] * invZ) * u[o];

    xp += D_IN;
    Wp += N_OUT * D_OUT * D_IN;
  }

  float* Pp = &P[(size_t)(ng * B + b) * OJ + j];
#pragma unroll
  for (int o = 0; o < N_OUT; ++o) Pp[o * D_OUT] = s[o];
}

// ---------------- reduce partials over n-groups + squash; optionally add previous v ----------------
__global__ __launch_bounds__(256) void caps_reduce(const float* __restrict__ P,
                                                   float scale,
                                                   const float* __restrict__ vprev,
                                                   float* __restrict__ vout) {
  const int idx = blockIdx.x * 256 + threadIdx.x;  // b*160 + o*16 + j, 0..40959
  float s = 0.f;
#pragma unroll 4
  for (int g = 0; g < NG; ++g) s += P[(size_t)g * PSTRIDE + idx];
  s *= scale;

  // squash over j (16 consecutive lanes = one (b,o))
  float sq = s * s;
  sq += __shfl_xor(sq, 1, 16);
  sq += __shfl_xor(sq, 2, 16);
  sq += __shfl_xor(sq, 4, 16);
  sq += __shfl_xor(sq, 8, 16);

  float v = s * (sq / (1.f + sq)) * rsqrtf(sq + 1e-8f);
  if (vprev != nullptr) v += vprev[idx];
  vout[idx] = v;
}

extern "C" void kernel_launch(void* const* d_in, const int* in_sizes, int n_in,
                              void* d_out, int out_size, void* d_ws, size_t ws_size,
                              hipStream_t stream) {
  const float* x = (const float*)d_in[0];   // (256,1152,8)
  const float* W = (const float*)d_in[1];   // (1,1152,10,16,8)
  float* out = (float*)d_out;               // (256,10,16) f32

  float* P   = (float*)d_ws;                // NG * 40960 floats
  float* v1  = P + (size_t)NG * PSTRIDE;    // 40960 floats
  float* v12 = v1 + PSTRIDE;                // 40960 floats (v1+v2)

  const dim3 grid(NG, NBG), blk(256);

  // iter 1: c uniform -> s1 (scale 1/10 folded into reduce), v1 = squash(s1)
  caps_pass1<<<grid, blk, 0, stream>>>(x, W, P);
  caps_reduce<<<PSTRIDE / 256, 256, 0, stream>>>(P, 0.1f, nullptr, v1);

  // iter 2: logits = u.v1 -> s2, v2; emit v12 = v1 + v2 for next pass
  caps_pass23<<<grid, blk, 0, stream>>>(x, W, v1, P);
  caps_reduce<<<PSTRIDE / 256, 256, 0, stream>>>(P, 1.0f, v1, v12);

  // iter 3: logits = u.(v1+v2) -> s3, v3 = output
  caps_pass23<<<grid, blk, 0, stream>>>(x, W, v12, P);
  caps_reduce<<<PSTRIDE / 256, 256, 0, stream>>>(P, 1.0f, nullptr, out);
}

// Round 2
// 182.425 us; speedup vs baseline: 1.2845x; 1.2845x over previous
//
#include <hip/hip_runtime.h>

#define B 256
#define N_IN 1152
#define D_IN 8
#define N_OUT 10
#define D_OUT 16
#define NC 8                       // n's per block
#define NGRP (N_IN / NC)           // 144 n-groups
#define BPB 16                     // batches per block
#define NBG (B / BPB)              // 16 b-groups
#define OJ (N_OUT * D_OUT)         // 160
#define SN (B * OJ)                // 40960 floats in s / v buffers

// ---- DPP rotate-reduce over a 16-lane row (pure VALU, no DS pipe) ----
template<int CTRL>
__device__ __forceinline__ float dpp_add(float x) {
  int y = __builtin_amdgcn_mov_dpp(__float_as_int(x), CTRL, 0xF, 0xF, false);
  return x + __int_as_float(y);
}
__device__ __forceinline__ float row_sum16(float x) {
  x = dpp_add<0x128>(x);  // row_ror:8
  x = dpp_add<0x124>(x);  // row_ror:4
  x = dpp_add<0x122>(x);  // row_ror:2
  x = dpp_add<0x121>(x);  // row_ror:1
  return x;               // every lane holds the row sum
}

__global__ __launch_bounds__(256) void caps_zero(float* __restrict__ s) {
  s[blockIdx.x * 256 + threadIdx.x] = 0.f;
}

// ---------------- pass 1: uniform coupling (1/10 folded into finish) ----------------
__global__ __launch_bounds__(256) void caps_pass1(const float* __restrict__ x,
                                                  const float* __restrict__ W,
                                                  float* __restrict__ s) {
  const int tid = threadIdx.x;
  const int bb = tid >> 4, j = tid & 15;
  const int b = blockIdx.y * BPB + bb;
  const int n0 = blockIdx.x * NC;

  float acc[N_OUT];
#pragma unroll
  for (int o = 0; o < N_OUT; ++o) acc[o] = 0.f;

  const float* xp = &x[(size_t)(b * N_IN + n0) * D_IN];
  const float* Wp = &W[((size_t)n0 * N_OUT * D_OUT + j) * D_IN];

  for (int nn = 0; nn < NC; ++nn) {
    const float4 xa = *reinterpret_cast<const float4*>(xp);
    const float4 xb = *reinterpret_cast<const float4*>(xp + 4);
#pragma unroll
    for (int o = 0; o < N_OUT; ++o) {
      const float4 wa = *reinterpret_cast<const float4*>(Wp + o * (D_OUT * D_IN));
      const float4 wb = *reinterpret_cast<const float4*>(Wp + o * (D_OUT * D_IN) + 4);
      acc[o] += wa.x*xa.x + wa.y*xa.y + wa.z*xa.z + wa.w*xa.w
              + wb.x*xb.x + wb.y*xb.y + wb.z*xb.z + wb.w*xb.w;
    }
    xp += D_IN;
    Wp += N_OUT * D_OUT * D_IN;
  }

  float* sp = &s[(size_t)b * OJ + j];
#pragma unroll
  for (int o = 0; o < N_OUT; ++o) unsafeAtomicAdd(sp + o * D_OUT, acc[o]);
}

// ---------------- pass 2/3: logits = u_hat . veff, softmax over o, weighted sum ----------------
__global__ __launch_bounds__(256) void caps_pass23(const float* __restrict__ x,
                                                   const float* __restrict__ W,
                                                   const float* __restrict__ veff,
                                                   float* __restrict__ s) {
  const int tid = threadIdx.x;
  const int bb = tid >> 4, j = tid & 15;
  const int b = blockIdx.y * BPB + bb;
  const int n0 = blockIdx.x * NC;

  // this thread's v values (n-invariant): coalesced, L2-hot (160 KB buffer)
  float vj[N_OUT];
  const float* vp = &veff[(size_t)b * OJ + j];
#pragma unroll
  for (int o = 0; o < N_OUT; ++o) vj[o] = vp[o * D_OUT];

  float acc[N_OUT];
#pragma unroll
  for (int o = 0; o < N_OUT; ++o) acc[o] = 0.f;

  const float* xp = &x[(size_t)(b * N_IN + n0) * D_IN];
  const float* Wp = &W[((size_t)n0 * N_OUT * D_OUT + j) * D_IN];

  for (int nn = 0; nn < NC; ++nn) {
    const float4 xa = *reinterpret_cast<const float4*>(xp);
    const float4 xb = *reinterpret_cast<const float4*>(xp + 4);
    float u[N_OUT];
#pragma unroll
    for (int o = 0; o < N_OUT; ++o) {
      const float4 wa = *reinterpret_cast<const float4*>(Wp + o * (D_OUT * D_IN));
      const float4 wb = *reinterpret_cast<const float4*>(Wp + o * (D_OUT * D_IN) + 4);
      u[o] = wa.x*xa.x + wa.y*xa.y + wa.z*xa.z + wa.w*xa.w
           + wb.x*xb.x + wb.y*xb.y + wb.z*xb.z + wb.w*xb.w;
    }
    // logits: 16-lane DPP reduce over j; all lanes get the sum
    // softmax over o without max-subtract: |logit| <= ~0.6, exp is safe
    float e[N_OUT], Z = 0.f;
#pragma unroll
    for (int o = 0; o < N_OUT; ++o) {
      e[o] = __expf(row_sum16(u[o] * vj[o]));
      Z += e[o];
    }
    const float invZ = 1.f / Z;
#pragma unroll
    for (int o = 0; o < N_OUT; ++o) acc[o] += (e[o] * invZ) * u[o];

    xp += D_IN;
    Wp += N_OUT * D_OUT * D_IN;
  }

  float* sp = &s[(size_t)b * OJ + j];
#pragma unroll
  for (int o = 0; o < N_OUT; ++o) unsafeAtomicAdd(sp + o * D_OUT, acc[o]);
}

// ---------------- squash + (optional) add vprev + (optional) re-zero s ----------------
__global__ __launch_bounds__(256) void caps_finish(float* __restrict__ s, float scale,
                                                   const float* __restrict__ vprev,
                                                   float* __restrict__ vout, int zero_s) {
  const int idx = blockIdx.x * 256 + threadIdx.x;  // b*160 + o*16 + j
  const float t = s[idx] * scale;
  const float sq = row_sum16(t * t);               // ||s||^2 over j (16-lane row)
  float v = t * (sq / (1.f + sq)) * rsqrtf(sq + 1e-8f);
  if (vprev != nullptr) v += vprev[idx];
  vout[idx] = v;
  if (zero_s) s[idx] = 0.f;
}

extern "C" void kernel_launch(void* const* d_in, const int* in_sizes, int n_in,
                              void* d_out, int out_size, void* d_ws, size_t ws_size,
                              hipStream_t stream) {
  const float* x = (const float*)d_in[0];   // (256,1152,8)
  const float* W = (const float*)d_in[1];   // (1,1152,10,16,8)
  float* out = (float*)d_out;               // (256,10,16)

  float* s   = (float*)d_ws;                // 40960 floats
  float* v1  = s + SN;
  float* v12 = v1 + SN;

  const dim3 grid(NGRP, NBG), blk(256);

  caps_zero<<<SN / 256, 256, 0, stream>>>(s);

  // iter 1: uniform c -> s1 ; v1 = squash(0.1*s1) ; s := 0
  caps_pass1<<<grid, blk, 0, stream>>>(x, W, s);
  caps_finish<<<SN / 256, 256, 0, stream>>>(s, 0.1f, nullptr, v1, 1);

  // iter 2: logits = u.v1 -> s2 ; v12 = v1 + squash(s2) ; s := 0
  caps_pass23<<<grid, blk, 0, stream>>>(x, W, v1, s);
  caps_finish<<<SN / 256, 256, 0, stream>>>(s, 1.0f, v1, v12, 1);

  // iter 3: logits = u.(v1+v2) -> s3 ; out = squash(s3)
  caps_pass23<<<grid, blk, 0, stream>>>(x, W, v12, s);
  caps_finish<<<SN / 256, 256, 0, stream>>>(s, 1.0f, nullptr, out, 0);
}